// Round 6
// baseline (390.943 us; speedup 1.0000x reference)
//
#include <hip/hip_runtime.h>
#include <hip/hip_bf16.h>

#define BS     4
#define NQ     10000
#define NV     13294
#define EMBED  256
#define HEADS  8
#define LEVELS 4
#define POINTS 4
#define DH     32

typedef __attribute__((ext_vector_type(8))) short short8;
typedef __attribute__((ext_vector_type(4))) float floatx4;

static __device__ __forceinline__ unsigned short f2b(float f) {
    __hip_bfloat16 h = __float2bfloat16(f);   // RNE
    return *(unsigned short*)&h;
}
static __device__ __forceinline__ float b2f(unsigned short u) {
    return __uint_as_float(((unsigned int)u) << 16);
}
static __device__ __forceinline__ unsigned int pk_bf16(float x, float y) {
    __hip_bfloat162 h = __float22bfloat162_rn(make_float2(x, y));  // v_cvt_pk_bf16_f32
    unsigned int u; __builtin_memcpy(&u, &h, 4); return u;
}

// ---------------------------------------------------------------------------
// Weight prep: transpose+cast to bf16 [N][K], concat (Woff|Ww) and (boff|bw).
// ---------------------------------------------------------------------------
__global__ __launch_bounds__(256) void prep_weights(
    const float* __restrict__ Wv,  const float* __restrict__ Woff,
    const float* __restrict__ boff,const float* __restrict__ Ww,
    const float* __restrict__ bw,  const float* __restrict__ Wo,
    unsigned short* __restrict__ Wvt, unsigned short* __restrict__ Wcatt,
    unsigned short* __restrict__ Wot, float* __restrict__ bcat)
{
    const int n = blockIdx.x;
    const int k = threadIdx.x;   // 0..255
    if (n < 256) {
        Wvt[n * 256 + k] = f2b(Wv[k * 256 + n]);
    } else if (n < 512) {
        Wcatt[(n - 256) * 256 + k] = f2b(Woff[k * 256 + (n - 256)]);
    } else if (n < 640) {
        Wcatt[(n - 256) * 256 + k] = f2b(Ww[k * 128 + (n - 512)]);
    } else {
        Wot[(n - 640) * 256 + k] = f2b(Wo[k * 256 + (n - 640)]);
    }
    if (n == 0) {
        for (int j = k; j < 384; j += 256)
            bcat[j] = (j < 256) ? boff[j] : bw[j - 256];
    }
}

// ---------------------------------------------------------------------------
// B-resident streaming GEMM.
// 1024 threads = 16 waves (4m x 4n). LDS = one 128-col x 256-k bf16 B-panel
// (exactly 64 KB, XOR-swizzled 16B chunks: free-2-way bank access). Panel is
// staged ONCE, one __syncthreads, then each wave streams its 64-row x 32-col
// tile of A with direct global loads -> ZERO barriers in the K-loop, loads
// always in flight. A is read exactly once per panel (L3 absorbs re-reads).
// MODE 0: bf16 out; 2: fp32 out + residual. AF32: A fp32, convert inline.
// Bsh chunk index: kc = 8-ushort (16 B) chunk, swizzled by n&7.
// ---------------------------------------------------------------------------
#define BIDX(n, kc) ((n) * 256 + ((((kc) ^ ((n) & 7))) << 3))

template<int MODE, bool AF32>
static __device__ __forceinline__ void gemm_stream(
    const void* __restrict__ Aptr, int M,
    const unsigned short* __restrict__ Bt, int bn0,
    const float* __restrict__ bias,
    void* __restrict__ Cv, int ldc,
    const float* __restrict__ residual,
    int mblk)
{
    __shared__ __align__(16) unsigned short Bsh[128 * 256];   // 64 KB

    const int t = threadIdx.x;

    // ---- stage B panel: rows bn0..bn0+127 of Bt, 64 B per thread ----
    {
        const int r  = t >> 3;             // 0..127
        const int cb = (t & 7) * 4;        // base 16B-chunk, 4 chunks/thread
        const uint4* src = (const uint4*)&Bt[(size_t)(bn0 + r) * 256 + cb * 8];
        #pragma unroll
        for (int j = 0; j < 4; ++j)
            *(uint4*)&Bsh[BIDX(r, cb + j)] = src[j];
    }
    __syncthreads();

    const int lane = t & 63;
    const int wv   = t >> 6;               // 0..15
    const int wm   = mblk * 256 + (wv >> 2) * 64;
    const int wn   = (wv & 3) * 32;        // col offset within panel
    const int lr   = lane & 15;
    const int lk   = (lane >> 4) * 8;

    floatx4 acc[4][2] = {};

    int arow[4];
    #pragma unroll
    for (int mt = 0; mt < 4; ++mt)
        arow[mt] = min(wm + mt * 16 + lr, M - 1);   // clamped loads; writes guarded

    #pragma unroll 4
    for (int k0 = 0; k0 < 256; k0 += 32) {
        const int kc = (k0 + lk) >> 3;
        short8 bf[2];
        #pragma unroll
        for (int nt = 0; nt < 2; ++nt)
            bf[nt] = *(const short8*)&Bsh[BIDX(wn + nt * 16 + lr, kc)];

        short8 af[4];
        #pragma unroll
        for (int mt = 0; mt < 4; ++mt) {
            if (AF32) {
                const float4* s = (const float4*)((const float*)Aptr + (size_t)arow[mt] * 256 + k0 + lk);
                const float4 f0 = s[0], f1 = s[1];
                union { short8 v; unsigned int u[4]; } cv;
                cv.u[0] = pk_bf16(f0.x, f0.y);
                cv.u[1] = pk_bf16(f0.z, f0.w);
                cv.u[2] = pk_bf16(f1.x, f1.y);
                cv.u[3] = pk_bf16(f1.z, f1.w);
                af[mt] = cv.v;
            } else {
                af[mt] = *(const short8*)&((const unsigned short*)Aptr)[(size_t)arow[mt] * 256 + k0 + lk];
            }
        }

        #pragma unroll
        for (int mt = 0; mt < 4; ++mt) {
            #pragma unroll
            for (int nt = 0; nt < 2; ++nt)
                acc[mt][nt] = __builtin_amdgcn_mfma_f32_16x16x32_bf16(af[mt], bf[nt], acc[mt][nt], 0, 0, 0);
        }
    }

    // epilogue: C/D layout col = lane&15, row = (lane>>4)*4 + reg
    const int rbase = wm + (lane >> 4) * 4;
    #pragma unroll
    for (int nt = 0; nt < 2; ++nt) {
        const int col = bn0 + wn + nt * 16 + lr;
        const float bb = bias[col];
        #pragma unroll
        for (int mt = 0; mt < 4; ++mt) {
            #pragma unroll
            for (int r = 0; r < 4; ++r) {
                const int row = rbase + mt * 16 + r;
                if (row < M) {
                    float val = acc[mt][nt][r] + bb;
                    if (MODE == 2) val += residual[(size_t)row * ldc + col];
                    if (MODE == 0)
                        ((unsigned short*)Cv)[(size_t)row * ldc + col] = f2b(val);
                    else
                        ((float*)Cv)[(size_t)row * ldc + col] = val;
                }
            }
        }
    }
}

// Fused GEMM-V + GEMM-proj.
// g1: 208 row-blocks x 2 panels = 416 blocks; g2: 157 x 3 = 471 blocks.
__global__ __launch_bounds__(1024, 4) void gemm_fused12(
    const float* __restrict__ value, const float* __restrict__ query,
    const unsigned short* __restrict__ Wvt, const unsigned short* __restrict__ Wcatt,
    const float* __restrict__ bv, const float* __restrict__ bcat,
    unsigned short* __restrict__ vout, unsigned short* __restrict__ projout)
{
    const unsigned int bid = blockIdx.x;
    if (bid < 416u) {
        gemm_stream<0, true>(value, BS * NV, Wvt, (int)(bid & 1) * 128, bv,
                             vout, 256, nullptr, (int)(bid >> 1));
    } else {
        const unsigned int b2 = bid - 416u;
        gemm_stream<0, true>(query, BS * NQ, Wcatt, (int)(b2 % 3u) * 128, bcat,
                             projout, 384, nullptr, (int)(b2 / 3u));
    }
}

// out = msda @ Wo + bo + query  (fp32 out). 157 row-blocks x 2 panels.
__global__ __launch_bounds__(1024, 4) void gemm_out(
    const unsigned short* __restrict__ msda, const unsigned short* __restrict__ Wot,
    const float* __restrict__ bo, float* __restrict__ out,
    const float* __restrict__ query)
{
    const unsigned int bid = blockIdx.x;
    gemm_stream<2, false>(msda, BS * NQ, Wot, (int)(bid & 1) * 128, bo,
                          out, 256, query, (int)(bid >> 1));
}

// ---------------------------------------------------------------------------
// Fused softmax + bilinear sampling, two-phase (proj bf16).
// ---------------------------------------------------------------------------
__global__ __launch_bounds__(256) void msda_sample(
    const unsigned short* __restrict__ v,
    const unsigned short* __restrict__ proj,
    const float* __restrict__ rp,
    unsigned short* __restrict__ out)
{
    __shared__ __align__(16) unsigned int taps[4 * 1056];  // 4 waves * 8 heads * 528 B

    const int wave = threadIdx.x >> 6;
    const int lane = threadIdx.x & 63;
    const int q = blockIdx.x * 4 + wave;
    const int b = blockIdx.y;
    const int rowq = b * NQ + q;
    const unsigned short* prow = proj + (size_t)rowq * 384;

    // ---- phase A: lane = h*8+i owns combos c = 2i, 2i+1 ----
    const int hA = lane >> 3;
    const int li = lane & 7;
    const int c0 = li * 2;

    const ushort2 lgu = *(const ushort2*)&prow[256 + hA * 16 + c0];
    const float lgx = b2f(lgu.x), lgy = b2f(lgu.y);
    float mx = fmaxf(lgx, lgy);
    mx = fmaxf(mx, __shfl_xor(mx, 1));
    mx = fmaxf(mx, __shfl_xor(mx, 2));
    mx = fmaxf(mx, __shfl_xor(mx, 4));
    const float e0 = __expf(lgx - mx);
    const float e1 = __expf(lgy - mx);
    float ssum = e0 + e1;
    ssum += __shfl_xor(ssum, 1);
    ssum += __shfl_xor(ssum, 2);
    ssum += __shfl_xor(ssum, 4);
    const float inv = 1.0f / ssum;

    const int l = c0 >> 2;   // both combos share the level
    const int Wl = (l == 0) ? 100 : (l == 1) ? 50 : (l == 2) ? 25 : 13;
    const int st = (l == 0) ? 0 : (l == 1) ? 10000 : (l == 2) ? 12500 : 13125;
    const int Hl = Wl;
    const float fW = (float)Wl, fH = (float)Hl;

    const float2 rxy = *(const float2*)&rp[((size_t)rowq * 4 + l) * 2];

    unsigned int* tbase = taps + wave * 1056 + hA * 132;

    #pragma unroll
    for (int cc = 0; cc < 2; ++cc) {
        const int c = c0 + cc;
        const ushort2 oxyu = *(const ushort2*)&prow[hA * 32 + c * 2];
        const float ox = b2f(oxyu.x), oy = b2f(oxyu.y);
        const float aww = (cc ? e1 : e0) * inv;
        const float x = fmaf(rxy.x, fW, ox) - 0.5f;
        const float y = fmaf(rxy.y, fH, oy) - 0.5f;
        const float x0f = floorf(x), y0f = floorf(y);
        const float fx = x - x0f, fy = y - y0f;
        const int ix = (int)x0f, iy = (int)y0f;
        const float wxv[2] = {1.f - fx, fx};
        const float wyv[2] = {1.f - fy, fy};

        uint4 ent[2];
        #pragma unroll
        for (int tp = 0; tp < 4; ++tp) {
            const int dy = tp >> 1, dx = tp & 1;
            const int xi = ix + dx, yi = iy + dy;
            const bool ok = (xi >= 0) && (xi < Wl) && (yi >= 0) && (yi < Hl);
            const int cx = min(max(xi, 0), Wl - 1);
            const int cy = min(max(yi, 0), Hl - 1);
            const unsigned int off = (unsigned int)(st + cy * Wl + cx) * 512u + (unsigned int)hA * 64u;
            const float w = ok ? wyv[dy] * wxv[dx] * aww : 0.f;
            ((unsigned int*)&ent[tp >> 1])[(tp & 1) * 2 + 0] = off;
            ((unsigned int*)&ent[tp >> 1])[(tp & 1) * 2 + 1] = __float_as_uint(w);
        }
        *(uint4*)&tbase[(c * 4 + 0) * 2] = ent[0];
        *(uint4*)&tbase[(c * 4 + 2) * 2] = ent[1];
    }

    __syncthreads();

    // ---- phase B: lane = h*8+i owns dims i*4..i*4+3 ----
    const int h = lane >> 3;
    const unsigned int lane_off = (unsigned int)(lane & 7) * 8u;
    const char* vbase = (const char*)v + (size_t)b * NV * 512;   // wave-uniform
    const uint4* tp4 = (const uint4*)(taps + wave * 1056 + h * 132);

    float a0 = 0.f, a1 = 0.f, a2 = 0.f, a3 = 0.f;
    #pragma unroll 8
    for (int j = 0; j < 32; ++j) {
        const uint4 ee = tp4[j];
        const uint2 g0 = *(const uint2*)(vbase + (ee.x + lane_off));
        const uint2 g1 = *(const uint2*)(vbase + (ee.z + lane_off));
        const float w0 = __uint_as_float(ee.y);
        const float w1 = __uint_as_float(ee.w);
        a0 = fmaf(w0, __uint_as_float(g0.x << 16), a0);
        a1 = fmaf(w0, __uint_as_float(g0.x & 0xFFFF0000u), a1);
        a2 = fmaf(w0, __uint_as_float(g0.y << 16), a2);
        a3 = fmaf(w0, __uint_as_float(g0.y & 0xFFFF0000u), a3);
        a0 = fmaf(w1, __uint_as_float(g1.x << 16), a0);
        a1 = fmaf(w1, __uint_as_float(g1.x & 0xFFFF0000u), a1);
        a2 = fmaf(w1, __uint_as_float(g1.y << 16), a2);
        a3 = fmaf(w1, __uint_as_float(g1.y & 0xFFFF0000u), a3);
    }

    ushort4 o;
    o.x = f2b(a0); o.y = f2b(a1); o.z = f2b(a2); o.w = f2b(a3);
    *(ushort4*)&out[(size_t)rowq * 256 + h * 32 + (lane & 7) * 4] = o;
}

// ---------------------------------------------------------------------------
// kernel_launch
// ---------------------------------------------------------------------------
extern "C" void kernel_launch(void* const* d_in, const int* in_sizes, int n_in,
                              void* d_out, int out_size, void* d_ws, size_t ws_size,
                              hipStream_t stream) {
    const float* query = (const float*)d_in[0];
    const float* value = (const float*)d_in[1];
    const float* rp    = (const float*)d_in[2];
    const float* Wv    = (const float*)d_in[4];
    const float* bv    = (const float*)d_in[5];
    const float* Woff  = (const float*)d_in[6];
    const float* boff  = (const float*)d_in[7];
    const float* Ww    = (const float*)d_in[8];
    const float* bw    = (const float*)d_in[9];
    const float* Wo    = (const float*)d_in[10];
    const float* bo    = (const float*)d_in[11];
    float* out = (float*)d_out;

    const int Mq = BS * NQ;   // 40000
    const int Mv = BS * NV;   // 53176

    char* ws = (char*)d_ws;
    const size_t SZ_MSDA = (size_t)Mq * 256 * 2;
    const size_t SZ_V    = (size_t)Mv * 256 * 2;
    const size_t SZ_PROJ = (size_t)Mq * 384 * 2;
    unsigned short* msda  = (unsigned short*)(ws);
    unsigned short* v_bf  = (unsigned short*)(ws + SZ_MSDA);
    unsigned short* proj  = (unsigned short*)(ws + SZ_MSDA + SZ_V);
    char* wp = ws + SZ_MSDA + SZ_V + SZ_PROJ;
    unsigned short* Wvt   = (unsigned short*)(wp);
    unsigned short* Wcatt = (unsigned short*)(wp + 256 * 256 * 2);
    unsigned short* Wot   = (unsigned short*)(wp + 256 * 256 * 2 + 384 * 256 * 2);
    float*          bcat  = (float*)(wp + 256 * 256 * 2 + 384 * 256 * 2 + 256 * 256 * 2);

    prep_weights<<<896, 256, 0, stream>>>(Wv, Woff, boff, Ww, bw, Wo, Wvt, Wcatt, Wot, bcat);

    // v = value @ Wv + bv (bf16) AND proj = query @ [Woff|Ww] + bias (bf16)
    // g1: ceil(53176/256)=208 row-blocks x 2 panels; g2: ceil(40000/256)=157 x 3
    gemm_fused12<<<416 + 471, 1024, 0, stream>>>(
        value, query, Wvt, Wcatt, bv, bcat, v_bf, proj);

    // softmax + sampling -> msda (bf16)
    msda_sample<<<dim3(NQ / 4, BS), 256, 0, stream>>>(v_bf, proj, rp, msda);

    // out = msda @ Wo + bo + query
    gemm_out<<<157 * 2, 1024, 0, stream>>>(msda, Wot, bo, out, query);
}

// Round 7
// 345.427 us; speedup vs baseline: 1.1318x; 1.1318x over previous
//
#include <hip/hip_runtime.h>
#include <hip/hip_bf16.h>

#define BS     4
#define NQ     10000
#define NV     13294
#define EMBED  256
#define HEADS  8
#define LEVELS 4
#define POINTS 4
#define DH     32

typedef __attribute__((ext_vector_type(8))) short short8;
typedef __attribute__((ext_vector_type(4))) float floatx4;

static __device__ __forceinline__ unsigned short f2b(float f) {
    __hip_bfloat16 h = __float2bfloat16(f);   // RNE
    return *(unsigned short*)&h;
}
static __device__ __forceinline__ float b2f(unsigned short u) {
    return __uint_as_float(((unsigned int)u) << 16);
}
static __device__ __forceinline__ unsigned int pk_bf16(float x, float y) {
    __hip_bfloat162 h = __float22bfloat162_rn(make_float2(x, y));  // v_cvt_pk_bf16_f32
    unsigned int u; __builtin_memcpy(&u, &h, 4); return u;
}
// async global->LDS, 16 B per lane; lds dest = wave-uniform base + lane*16
static __device__ __forceinline__ void dma16(const unsigned short* g, unsigned short* l) {
    __builtin_amdgcn_global_load_lds(
        (const __attribute__((address_space(1))) unsigned int*)g,
        (__attribute__((address_space(3))) unsigned int*)l,
        16, 0, 0);
}

// ---------------------------------------------------------------------------
// Weight prep: transpose+cast to bf16 [N][K], concat (Woff|Ww) and (boff|bw).
// ---------------------------------------------------------------------------
__global__ __launch_bounds__(256) void prep_weights(
    const float* __restrict__ Wv,  const float* __restrict__ Woff,
    const float* __restrict__ boff,const float* __restrict__ Ww,
    const float* __restrict__ bw,  const float* __restrict__ Wo,
    unsigned short* __restrict__ Wvt, unsigned short* __restrict__ Wcatt,
    unsigned short* __restrict__ Wot, float* __restrict__ bcat)
{
    const int n = blockIdx.x;
    const int k = threadIdx.x;   // 0..255
    if (n < 256) {
        Wvt[n * 256 + k] = f2b(Wv[k * 256 + n]);
    } else if (n < 512) {
        Wcatt[(n - 256) * 256 + k] = f2b(Woff[k * 256 + (n - 256)]);
    } else if (n < 640) {
        Wcatt[(n - 256) * 256 + k] = f2b(Ww[k * 128 + (n - 512)]);
    } else {
        Wot[(n - 640) * 256 + k] = f2b(Wo[k * 256 + (n - 640)]);
    }
    if (n == 0) {
        for (int j = k; j < 384; j += 256)
            bcat[j] = (j < 256) ? boff[j] : bw[j - 256];
    }
}

// ---------------------------------------------------------------------------
// Pipelined bf16 MFMA GEMM: C[M x N] = A[M x 256] @ Bt^T + bias.
// 128x128 tile / 256 threads (4 waves, 2x2 of 64x64 wave tiles).
// A: prefetched to regs one iter ahead (issued AFTER the publish barrier, so
//    the next barrier's vmcnt(0) drain sees loads that flew across a whole
//    compute phase); fp32->bf16 convert deferred to the write phase.
// B: global_load_lds dwordx4 into double-buffered LDS panel, XOR-swizzled
//    (chunk ^= row&7) so fragment ds_read_b128 is 2-way max (free).
// LDS: A 128x72 ush (18 KB, +8 pad) + B 2x128x64 ush (32 KB) = 50 KB.
// MODE 0: bf16 out; 2: fp32 out + residual. AF32: A fp32, convert inline.
// ---------------------------------------------------------------------------
#define ASTR 72

template<int MODE, bool AF32>
static __device__ __forceinline__ void gemm_body(
    unsigned short* As, unsigned short* Bsh,   // Bsh = [2][128*64]
    const void* __restrict__ Aptr, int M,
    const unsigned short* __restrict__ Bt,
    const float* __restrict__ bias,
    void* __restrict__ Cv, int ldc,
    const float* __restrict__ residual,
    int mb, int nb)
{
    const int t  = threadIdx.x;
    const int m0 = mb * 128;
    const int n0 = nb * 128;

    const int wv   = t >> 6;
    const int lane = t & 63;
    const int wm   = (wv & 1) * 64;
    const int wn   = (wv >> 1) * 64;
    const int lr   = lane & 15;
    const int lk   = (lane >> 4) * 8;

    // staging ids
    const int ar = t >> 1;            // A row 0..127
    const int ac = (t & 1) * 32;      // A col offset (elements)
    const bool arow_ok = (m0 + ar) < M;
    // B dma ids (per j): row = (wv*4+j)*8 + (lane>>3), chunk = (lane&7)^(row&7)
    const int brow_lo = lane >> 3;    // 0..7
    const int bkcs    = lane & 7;

    floatx4 acc[4][4] = {};
    float4 a32[8];
    uint4  a16[4];

    // ---- prologue: prefetch iter 0 ----
    {
        if (AF32) {
            const float4* s = (const float4*)((const float*)Aptr + (size_t)(m0 + ar) * 256 + ac);
            #pragma unroll
            for (int i = 0; i < 8; ++i) a32[i] = arow_ok ? s[i] : make_float4(0.f,0.f,0.f,0.f);
        } else {
            const uint4* s = (const uint4*)((const unsigned short*)Aptr + (size_t)(m0 + ar) * 256 + ac);
            #pragma unroll
            for (int i = 0; i < 4; ++i) a16[i] = arow_ok ? s[i] : make_uint4(0,0,0,0);
        }
        #pragma unroll
        for (int j = 0; j < 4; ++j) {
            const int row = (wv * 4 + j) * 8 + brow_lo;
            const int kc  = bkcs ^ (row & 7);
            dma16(Bt + (size_t)(n0 + row) * 256 + kc * 8,
                  &Bsh[(((wv * 4 + j) * 64 + lane) * 8)]);
        }
    }

    #pragma unroll
    for (int it = 0; it < 4; ++it) {
        const int buf = it & 1;
        __syncthreads();   // consumers of As / this B buf done; drains prefetched loads
        {
            uint4 w[4];
            if (AF32) {
                #pragma unroll
                for (int i = 0; i < 4; ++i) {
                    w[i].x = pk_bf16(a32[2*i].x, a32[2*i].y);
                    w[i].y = pk_bf16(a32[2*i].z, a32[2*i].w);
                    w[i].z = pk_bf16(a32[2*i+1].x, a32[2*i+1].y);
                    w[i].w = pk_bf16(a32[2*i+1].z, a32[2*i+1].w);
                }
            } else {
                #pragma unroll
                for (int i = 0; i < 4; ++i) w[i] = a16[i];
            }
            uint4* ad = (uint4*)&As[ar * ASTR + ac];
            ad[0] = w[0]; ad[1] = w[1]; ad[2] = w[2]; ad[3] = w[3];
        }
        __syncthreads();   // publish A + B(buf)

        if (it < 3) {      // prefetch iter it+1 (flies across the compute below)
            const int k0 = (it + 1) * 64;
            if (AF32) {
                const float4* s = (const float4*)((const float*)Aptr + (size_t)(m0 + ar) * 256 + k0 + ac);
                #pragma unroll
                for (int i = 0; i < 8; ++i) a32[i] = arow_ok ? s[i] : make_float4(0.f,0.f,0.f,0.f);
            } else {
                const uint4* s = (const uint4*)((const unsigned short*)Aptr + (size_t)(m0 + ar) * 256 + k0 + ac);
                #pragma unroll
                for (int i = 0; i < 4; ++i) a16[i] = arow_ok ? s[i] : make_uint4(0,0,0,0);
            }
            unsigned short* bdst = Bsh + (buf ^ 1) * (128 * 64);
            #pragma unroll
            for (int j = 0; j < 4; ++j) {
                const int row = (wv * 4 + j) * 8 + brow_lo;
                const int kc  = bkcs ^ (row & 7);
                dma16(Bt + (size_t)(n0 + row) * 256 + k0 + kc * 8,
                      &bdst[(((wv * 4 + j) * 64 + lane) * 8)]);
            }
        }

        const unsigned short* bsrc = Bsh + buf * (128 * 64);
        #pragma unroll
        for (int kk = 0; kk < 64; kk += 32) {
            const int kcl = (kk + lk) >> 3;
            short8 bf[4];
            #pragma unroll
            for (int nt = 0; nt < 4; ++nt) {
                const int n = wn + nt * 16 + lr;
                bf[nt] = *(const short8*)&bsrc[(n * 8 + (kcl ^ (n & 7))) * 8];
            }
            #pragma unroll
            for (int mt = 0; mt < 4; ++mt) {
                const short8 af = *(const short8*)&As[(wm + mt * 16 + lr) * ASTR + kk + lk];
                #pragma unroll
                for (int nt = 0; nt < 4; ++nt)
                    acc[mt][nt] = __builtin_amdgcn_mfma_f32_16x16x32_bf16(af, bf[nt], acc[mt][nt], 0, 0, 0);
            }
        }
    }

    // epilogue: C/D layout col = lane&15, row = (lane>>4)*4 + reg
    const int rbase = m0 + wm + (lane >> 4) * 4;
    #pragma unroll
    for (int nt = 0; nt < 4; ++nt) {
        const int col = n0 + wn + nt * 16 + lr;
        const float bb = bias[col];
        #pragma unroll
        for (int mt = 0; mt < 4; ++mt) {
            #pragma unroll
            for (int r = 0; r < 4; ++r) {
                const int row = rbase + mt * 16 + r;
                if (row < M) {
                    float val = acc[mt][nt][r] + bb;
                    if (MODE == 2) val += residual[(size_t)row * ldc + col];
                    if (MODE == 0)
                        ((unsigned short*)Cv)[(size_t)row * ldc + col] = f2b(val);
                    else
                        ((float*)Cv)[(size_t)row * ldc + col] = val;
                }
            }
        }
    }
}

// Fused GEMM-V + GEMM-proj (independent, one dispatch).
// blocks [0, 832): v = value @ Wv + bv          (416 m-blocks x 2 n-panels)
// blocks [832,1771): proj = query @ Wcat + bcat (313 m-blocks x 3 n-panels)
__global__ __launch_bounds__(256) void gemm_fused12(
    const float* __restrict__ value, const float* __restrict__ query,
    const unsigned short* __restrict__ Wvt, const unsigned short* __restrict__ Wcatt,
    const float* __restrict__ bv, const float* __restrict__ bcat,
    unsigned short* __restrict__ vout, unsigned short* __restrict__ projout)
{
    __shared__ __align__(16) unsigned short As[128 * ASTR];
    __shared__ __align__(16) unsigned short Bsh[2 * 128 * 64];
    const unsigned int bid = blockIdx.x;
    if (bid < 832u) {
        gemm_body<0, true>(As, Bsh, value, BS * NV, Wvt, bv, vout, 256, nullptr,
                           (int)(bid >> 1), (int)(bid & 1));
    } else {
        const unsigned int b2 = bid - 832u;
        gemm_body<0, true>(As, Bsh, query, BS * NQ, Wcatt, bcat, projout, 384, nullptr,
                           (int)(b2 / 3u), (int)(b2 % 3u));
    }
}

// out = msda @ Wo + bo + query  (fp32 out + residual)
__global__ __launch_bounds__(256) void gemm_out(
    const unsigned short* __restrict__ msda, const unsigned short* __restrict__ Wot,
    const float* __restrict__ bo, float* __restrict__ out,
    const float* __restrict__ query)
{
    __shared__ __align__(16) unsigned short As[128 * ASTR];
    __shared__ __align__(16) unsigned short Bsh[2 * 128 * 64];
    gemm_body<2, false>(As, Bsh, msda, BS * NQ, Wot, bo, out, 256, query,
                        (int)blockIdx.x, (int)blockIdx.y);
}

// ---------------------------------------------------------------------------
// Fused softmax + bilinear sampling, two-phase (proj bf16). Unchanged (93 us).
// ---------------------------------------------------------------------------
__global__ __launch_bounds__(256) void msda_sample(
    const unsigned short* __restrict__ v,
    const unsigned short* __restrict__ proj,
    const float* __restrict__ rp,
    unsigned short* __restrict__ out)
{
    __shared__ __align__(16) unsigned int taps[4 * 1056];  // 4 waves * 8 heads * 528 B

    const int wave = threadIdx.x >> 6;
    const int lane = threadIdx.x & 63;
    const int q = blockIdx.x * 4 + wave;
    const int b = blockIdx.y;
    const int rowq = b * NQ + q;
    const unsigned short* prow = proj + (size_t)rowq * 384;

    // ---- phase A: lane = h*8+i owns combos c = 2i, 2i+1 ----
    const int hA = lane >> 3;
    const int li = lane & 7;
    const int c0 = li * 2;

    const ushort2 lgu = *(const ushort2*)&prow[256 + hA * 16 + c0];
    const float lgx = b2f(lgu.x), lgy = b2f(lgu.y);
    float mx = fmaxf(lgx, lgy);
    mx = fmaxf(mx, __shfl_xor(mx, 1));
    mx = fmaxf(mx, __shfl_xor(mx, 2));
    mx = fmaxf(mx, __shfl_xor(mx, 4));
    const float e0 = __expf(lgx - mx);
    const float e1 = __expf(lgy - mx);
    float ssum = e0 + e1;
    ssum += __shfl_xor(ssum, 1);
    ssum += __shfl_xor(ssum, 2);
    ssum += __shfl_xor(ssum, 4);
    const float inv = 1.0f / ssum;

    const int l = c0 >> 2;   // both combos share the level
    const int Wl = (l == 0) ? 100 : (l == 1) ? 50 : (l == 2) ? 25 : 13;
    const int st = (l == 0) ? 0 : (l == 1) ? 10000 : (l == 2) ? 12500 : 13125;
    const int Hl = Wl;
    const float fW = (float)Wl, fH = (float)Hl;

    const float2 rxy = *(const float2*)&rp[((size_t)rowq * 4 + l) * 2];

    unsigned int* tbase = taps + wave * 1056 + hA * 132;

    #pragma unroll
    for (int cc = 0; cc < 2; ++cc) {
        const int c = c0 + cc;
        const ushort2 oxyu = *(const ushort2*)&prow[hA * 32 + c * 2];
        const float ox = b2f(oxyu.x), oy = b2f(oxyu.y);
        const float aww = (cc ? e1 : e0) * inv;
        const float x = fmaf(rxy.x, fW, ox) - 0.5f;
        const float y = fmaf(rxy.y, fH, oy) - 0.5f;
        const float x0f = floorf(x), y0f = floorf(y);
        const float fx = x - x0f, fy = y - y0f;
        const int ix = (int)x0f, iy = (int)y0f;
        const float wxv[2] = {1.f - fx, fx};
        const float wyv[2] = {1.f - fy, fy};

        uint4 ent[2];
        #pragma unroll
        for (int tp = 0; tp < 4; ++tp) {
            const int dy = tp >> 1, dx = tp & 1;
            const int xi = ix + dx, yi = iy + dy;
            const bool ok = (xi >= 0) && (xi < Wl) && (yi >= 0) && (yi < Hl);
            const int cx = min(max(xi, 0), Wl - 1);
            const int cy = min(max(yi, 0), Hl - 1);
            const unsigned int off = (unsigned int)(st + cy * Wl + cx) * 512u + (unsigned int)hA * 64u;
            const float w = ok ? wyv[dy] * wxv[dx] * aww : 0.f;
            ((unsigned int*)&ent[tp >> 1])[(tp & 1) * 2 + 0] = off;
            ((unsigned int*)&ent[tp >> 1])[(tp & 1) * 2 + 1] = __float_as_uint(w);
        }
        *(uint4*)&tbase[(c * 4 + 0) * 2] = ent[0];
        *(uint4*)&tbase[(c * 4 + 2) * 2] = ent[1];
    }

    __syncthreads();

    // ---- phase B: lane = h*8+i owns dims i*4..i*4+3 ----
    const int h = lane >> 3;
    const unsigned int lane_off = (unsigned int)(lane & 7) * 8u;
    const char* vbase = (const char*)v + (size_t)b * NV * 512;   // wave-uniform
    const uint4* tp4 = (const uint4*)(taps + wave * 1056 + h * 132);

    float a0 = 0.f, a1 = 0.f, a2 = 0.f, a3 = 0.f;
    #pragma unroll 8
    for (int j = 0; j < 32; ++j) {
        const uint4 ee = tp4[j];
        const uint2 g0 = *(const uint2*)(vbase + (ee.x + lane_off));
        const uint2 g1 = *(const uint2*)(vbase + (ee.z + lane_off));
        const float w0 = __uint_as_float(ee.y);
        const float w1 = __uint_as_float(ee.w);
        a0 = fmaf(w0, __uint_as_float(g0.x << 16), a0);
        a1 = fmaf(w0, __uint_as_float(g0.x & 0xFFFF0000u), a1);
        a2 = fmaf(w0, __uint_as_float(g0.y << 16), a2);
        a3 = fmaf(w0, __uint_as_float(g0.y & 0xFFFF0000u), a3);
        a0 = fmaf(w1, __uint_as_float(g1.x << 16), a0);
        a1 = fmaf(w1, __uint_as_float(g1.x & 0xFFFF0000u), a1);
        a2 = fmaf(w1, __uint_as_float(g1.y << 16), a2);
        a3 = fmaf(w1, __uint_as_float(g1.y & 0xFFFF0000u), a3);
    }

    ushort4 o;
    o.x = f2b(a0); o.y = f2b(a1); o.z = f2b(a2); o.w = f2b(a3);
    *(ushort4*)&out[(size_t)rowq * 256 + h * 32 + (lane & 7) * 4] = o;
}

// ---------------------------------------------------------------------------
// kernel_launch
// ---------------------------------------------------------------------------
extern "C" void kernel_launch(void* const* d_in, const int* in_sizes, int n_in,
                              void* d_out, int out_size, void* d_ws, size_t ws_size,
                              hipStream_t stream) {
    const float* query = (const float*)d_in[0];
    const float* value = (const float*)d_in[1];
    const float* rp    = (const float*)d_in[2];
    const float* Wv    = (const float*)d_in[4];
    const float* bv    = (const float*)d_in[5];
    const float* Woff  = (const float*)d_in[6];
    const float* boff  = (const float*)d_in[7];
    const float* Ww    = (const float*)d_in[8];
    const float* bw    = (const float*)d_in[9];
    const float* Wo    = (const float*)d_in[10];
    const float* bo    = (const float*)d_in[11];
    float* out = (float*)d_out;

    const int Mq = BS * NQ;   // 40000
    const int Mv = BS * NV;   // 53176

    char* ws = (char*)d_ws;
    const size_t SZ_MSDA = (size_t)Mq * 256 * 2;
    const size_t SZ_V    = (size_t)Mv * 256 * 2;
    const size_t SZ_PROJ = (size_t)Mq * 384 * 2;
    unsigned short* msda  = (unsigned short*)(ws);
    unsigned short* v_bf  = (unsigned short*)(ws + SZ_MSDA);
    unsigned short* proj  = (unsigned short*)(ws + SZ_MSDA + SZ_V);
    char* wp = ws + SZ_MSDA + SZ_V + SZ_PROJ;
    unsigned short* Wvt   = (unsigned short*)(wp);
    unsigned short* Wcatt = (unsigned short*)(wp + 256 * 256 * 2);
    unsigned short* Wot   = (unsigned short*)(wp + 256 * 256 * 2 + 384 * 256 * 2);
    float*          bcat  = (float*)(wp + 256 * 256 * 2 + 384 * 256 * 2 + 256 * 256 * 2);

    prep_weights<<<896, 256, 0, stream>>>(Wv, Woff, boff, Ww, bw, Wo, Wvt, Wcatt, Wot, bcat);

    // v = value @ Wv + bv (bf16) AND proj = query @ [Woff|Ww] + bias (bf16)
    gemm_fused12<<<832 + 939, 256, 0, stream>>>(
        value, query, Wvt, Wcatt, bv, bcat, v_bf, proj);

    // softmax + sampling -> msda (bf16)
    msda_sample<<<dim3(NQ / 4, BS), 256, 0, stream>>>(v_bf, proj, rp, msda);

    // out = msda @ Wo + bo + query
    gemm_out<<<dim3((Mq + 127) / 128, 2), 256, 0, stream>>>(msda, Wot, bo, out, query);
}